// Round 10
// baseline (43.704 us; speedup 1.0000x reference)
//
#include <hip/hip_runtime.h>

// GeometricAttention: B=4, N=256, FDIM=256, REL=16, H=8, D=32
//   K[b,i,j] = Kn[b,j] + rel[b,i,j] @ Wk_r          (Kn = nf@Wk_f + bk)
//   scores   = Q.Kn^T + Qr.rel^T                     (Qr = per-head Q @ Wk_r^T)
//   sum_j attn*V = attn@Vn + (attn@rel)@Wv_r         (Vn = nf@Wv_f + bv)
// Round 10: the r5-r9 ~42us invariant is the scalar-VALU floor (~470M MAC).
// Move the GEMM-shaped 57% (projections + out-GEMM, 268M MAC) onto MFMA
// (mfma_f32_16x16x32_bf16). k_attn = r9 minus output GEMM (unchanged core).

#define BB 4
#define NN 256
#define FD 256
#define RL 16
#define NH 8
#define HD 32

typedef __attribute__((ext_vector_type(8))) short bf16x8;   // 8 bf16 = 4 VGPR
typedef __attribute__((ext_vector_type(4))) float f32x4;

// ws layout (float offsets)
#define OFF_Q    0                         // float Q[b][i][f] (pre-scaled)
#define OFF_KN   (BB*NN*FD)                // ushort KnT[b][f][j]
#define OFF_VN   (OFF_KN + BB*NN*FD/2)     // ushort Vn[b][j][c]
#define OFF_WVB  (OFF_VN + BB*NN*FD/2)     // ushort wv[b][i][c]
#define OFF_NFB  (OFF_WVB + BB*NN*FD/2)    // ushort nfB[1024][256]
#define OFF_WT   (OFF_NFB + BB*NN*FD/2)    // ushort WT[4][c=256][k=256] (Wq,Wk_f,Wv_f,Wo)

#define ATP 260   // at[] row stride (floats)
#define RLT 130   // rldsT row stride (uints)

static __device__ __forceinline__ unsigned short f2bf(float x) {
  unsigned int u = __float_as_uint(x);
  unsigned int r = (u + 0x7fffu + ((u >> 16) & 1u)) >> 16;   // RNE
  return (unsigned short)r;
}
static __device__ __forceinline__ float bf2f(unsigned short h) {
  return __uint_as_float(((unsigned int)h) << 16);
}

// ---------------- Kernel 0: prep — nf->bf16 cast; W transposes to WT[c][k] bf16
__global__ __launch_bounds__(256) void k_prep(
    const float* __restrict__ nf,
    const float* __restrict__ Wq, const float* __restrict__ Wk,
    const float* __restrict__ Wv, const float* __restrict__ Wo,
    float* __restrict__ ws) {
  const int tid = threadIdx.x;
  const int sel = blockIdx.y;          // 0..3: transpose Wq/Wk_f/Wv_f/Wo; 4: nfB
  if (sel == 4) {
    unsigned short* nfB = (unsigned short*)(ws + OFF_NFB);
    const int base = blockIdx.x * 16384;
    #pragma unroll 8
    for (int k = 0; k < 64; ++k) {
      const int idx = base + k * 256 + tid;
      nfB[idx] = f2bf(nf[idx]);
    }
    return;
  }
  const float* W = (sel == 0) ? Wq : (sel == 1) ? Wk : (sel == 2) ? Wv : Wo;
  unsigned short* WT = (unsigned short*)(ws + OFF_WT) + sel * FD * FD;
  __shared__ unsigned short t[64][72];
  const int tx = blockIdx.x & 3, ty = blockIdx.x >> 2;   // 64x64 tile
  const int cx = tid & 63, r0 = tid >> 6;
  #pragma unroll
  for (int rr = r0; rr < 64; rr += 4)
    t[rr][cx] = f2bf(W[(ty * 64 + rr) * FD + tx * 64 + cx]);
  __syncthreads();
  #pragma unroll
  for (int rr = r0; rr < 64; rr += 4)
    WT[(tx * 64 + rr) * FD + ty * 64 + cx] = t[cx][rr];   // WT[c][k] = W[k][c]
}

// ---------------- Kernel 1: MFMA projections (Q / KnT / Vn)
// 64x64 tile per block; wave w = m-subtile; 4 n-subtiles per wave.
__global__ __launch_bounds__(256) void k_proj(
    const float* __restrict__ bq, const float* __restrict__ bk,
    const float* __restrict__ bv, float* __restrict__ ws) {
  const unsigned short* nfB = (const unsigned short*)(ws + OFF_NFB);
  const int mat = blockIdx.y >> 2;                 // 0=Q, 1=Kn, 2=Vn
  const int c0 = (blockIdx.y & 3) * 64;
  const int m0 = blockIdx.x * 64 + (threadIdx.x >> 6) * 16;
  const int l = threadIdx.x & 63;
  const unsigned short* WT = (const unsigned short*)(ws + OFF_WT) + mat * FD * FD;
  const int ar = l & 15, kg = l >> 4;              // frag row/col, k-group
  f32x4 acc[4];
  #pragma unroll
  for (int nt = 0; nt < 4; ++nt) acc[nt] = (f32x4){0.f, 0.f, 0.f, 0.f};
  #pragma unroll
  for (int ks = 0; ks < 8; ++ks) {
    bf16x8 a = *(const bf16x8*)(nfB + (m0 + ar) * FD + ks * 32 + kg * 8);
    #pragma unroll
    for (int nt = 0; nt < 4; ++nt) {
      bf16x8 b = *(const bf16x8*)(WT + (c0 + nt * 16 + ar) * FD + ks * 32 + kg * 8);
      acc[nt] = __builtin_amdgcn_mfma_f32_16x16x32_bf16(a, b, acc[nt], 0, 0, 0);
    }
  }
  // D[r][c]: r = m0 + kg*4 + i, c = c0 + nt*16 + ar   [m89-verified mapping]
  if (mat == 0) {
    const float scale = 0.17677669529663687f;      // 1/sqrt(32)
    float* Qo = ws + OFF_Q;
    #pragma unroll
    for (int nt = 0; nt < 4; ++nt) {
      const int cc = c0 + nt * 16 + ar;
      const float bb = bq[cc];
      #pragma unroll
      for (int i = 0; i < 4; ++i)
        Qo[(m0 + kg * 4 + i) * FD + cc] = (acc[nt][i] + bb) * scale;
    }
  } else if (mat == 1) {
    unsigned short* KnT = (unsigned short*)(ws + OFF_KN);
    const int b2 = m0 >> 8, j0 = (m0 & 255) + kg * 4;
    #pragma unroll
    for (int nt = 0; nt < 4; ++nt) {
      const int cc = c0 + nt * 16 + ar;
      const float bb = bk[cc];
      ushort4 v;
      v.x = f2bf(acc[nt][0] + bb); v.y = f2bf(acc[nt][1] + bb);
      v.z = f2bf(acc[nt][2] + bb); v.w = f2bf(acc[nt][3] + bb);
      *(ushort4*)&KnT[((size_t)b2 * FD + cc) * NN + j0] = v;
    }
  } else {
    unsigned short* Vn = (unsigned short*)(ws + OFF_VN);
    const int b2 = m0 >> 8;
    #pragma unroll
    for (int nt = 0; nt < 4; ++nt) {
      const int cc = c0 + nt * 16 + ar;
      const float bb = bv[cc];
      #pragma unroll
      for (int i = 0; i < 4; ++i) {
        const int j = (m0 & 255) + kg * 4 + i;
        Vn[((size_t)b2 * NN + j) * FD + cc] = f2bf(acc[nt][i] + bb);
      }
    }
  }
}

// ---------------- Kernel 2: qr + scores + softmax + arel + wv (r9 core, no out-GEMM)
__global__ __launch_bounds__(256, 4) void k_attn10(
    const float* __restrict__ rel,
    const float* __restrict__ Wk,
    const float* __restrict__ Wv,
    float* __restrict__ ws) {
  const float* Q = ws + OFF_Q;
  const unsigned short* KnB = (const unsigned short*)(ws + OFF_KN);
  const unsigned short* VnB = (const unsigned short*)(ws + OFF_VN);

  // XCD-chunked swizzle over 512 blocks (bijective)
  const int bid = (blockIdx.x & 7) * 64 + (blockIdx.x >> 3);
  const int b  = bid >> 7;
  const int i0 = (bid & 127) * 2;
  const int tid = threadIdx.x;
  const int l = tid & 63, w = tid >> 6;

  __shared__ float q[2][FD];                            // pre-scaled Q rows
  __shared__ float qrs[2][NH * RL];
  __shared__ float ar[2][NH * RL];
  __shared__ __align__(16) float at[2 * NH * ATP];
  __shared__ __align__(16) unsigned int rldsT[2 * RL * RLT];  // bf16-packed relT
  float* part = (float*)rldsT;                          // aliased after phase C

  q[0][tid] = Q[(b * NN + i0) * FD + tid];
  q[1][tid] = Q[(b * NN + i0 + 1) * FD + tid];

  // stage rel transposed + bf16-packed
  #pragma unroll
  for (int ii = 0; ii < 2; ++ii) {
    const float4* rp = (const float4*)(rel + ((size_t)(b * NN + i0 + ii)) * (NN * RL));
    #pragma unroll
    for (int m = 0; m < 2; ++m) {
      const int t = tid + 256 * m;       // 0..511
      const int jp = t >> 2, q4 = t & 3;
      float4 va = rp[8 * jp + q4];       // j = 2jp
      float4 vb = rp[8 * jp + 4 + q4];   // j = 2jp+1
      unsigned int* base = &rldsT[(ii * RL + 4 * q4) * RLT + jp];
      base[0]       = (unsigned int)f2bf(va.x) | ((unsigned int)f2bf(vb.x) << 16);
      base[RLT]     = (unsigned int)f2bf(va.y) | ((unsigned int)f2bf(vb.y) << 16);
      base[2 * RLT] = (unsigned int)f2bf(va.z) | ((unsigned int)f2bf(vb.z) << 16);
      base[3 * RLT] = (unsigned int)f2bf(va.w) | ((unsigned int)f2bf(vb.w) << 16);
    }
  }

  // qr for wave's two heads, both rows
  {
    const int ii = l >> 5, hh = (l >> 4) & 1, r = l & 15;
    const int h = 2 * w + hh;
    const float* wrow = Wk + (FD + r) * FD + h * HD;
    const float* qq = &q[ii][h * HD];
    float a = 0.f;
    #pragma unroll
    for (int d = 0; d < HD; ++d) a += qq[d] * wrow[d];
    qrs[ii][h * RL + r] = a;
  }
  __syncthreads();

  // ---- phase A: scores s[ii][hh][jj], j = 4l+jj, bf16 KnT
  float s[2][2][4];
  #pragma unroll
  for (int ii = 0; ii < 2; ++ii)
    #pragma unroll
    for (int hh = 0; hh < 2; ++hh)
      #pragma unroll
      for (int jj = 0; jj < 4; ++jj) s[ii][hh][jj] = 0.f;
  {
    const ushort4* kp = (const ushort4*)(KnB + ((size_t)b * FD + 64 * w) * NN) + l;
    #pragma unroll 2
    for (int dd = 0; dd < 8; ++dd) {
      float4 qv00 = *(const float4*)&q[0][64 * w + 4 * dd];
      float4 qv01 = *(const float4*)&q[0][64 * w + 32 + 4 * dd];
      float4 qv10 = *(const float4*)&q[1][64 * w + 4 * dd];
      float4 qv11 = *(const float4*)&q[1][64 * w + 32 + 4 * dd];
      #pragma unroll
      for (int e = 0; e < 4; ++e) {
        ushort4 u0 = kp[(4 * dd + e) * (NN / 4)];        // head 2w
        ushort4 u1 = kp[(32 + 4 * dd + e) * (NN / 4)];   // head 2w+1
        float4 k0 = make_float4(bf2f(u0.x), bf2f(u0.y), bf2f(u0.z), bf2f(u0.w));
        float4 k1 = make_float4(bf2f(u1.x), bf2f(u1.y), bf2f(u1.z), bf2f(u1.w));
        const float a0 = (&qv00.x)[e], a1 = (&qv01.x)[e];
        const float b0 = (&qv10.x)[e], b1 = (&qv11.x)[e];
        s[0][0][0] += a0 * k0.x; s[0][0][1] += a0 * k0.y;
        s[0][0][2] += a0 * k0.z; s[0][0][3] += a0 * k0.w;
        s[1][0][0] += b0 * k0.x; s[1][0][1] += b0 * k0.y;
        s[1][0][2] += b0 * k0.z; s[1][0][3] += b0 * k0.w;
        s[0][1][0] += a1 * k1.x; s[0][1][1] += a1 * k1.y;
        s[0][1][2] += a1 * k1.z; s[0][1][3] += a1 * k1.w;
        s[1][1][0] += b1 * k1.x; s[1][1][1] += b1 * k1.y;
        s[1][1][2] += b1 * k1.z; s[1][1][3] += b1 * k1.w;
      }
    }
  }

  // ---- rel-term: s += qr . relT
  #pragma unroll
  for (int ii = 0; ii < 2; ++ii) {
    #pragma unroll
    for (int r = 0; r < RL; ++r) {
      uint2 u = *(const uint2*)&rldsT[(ii * RL + r) * RLT + 2 * l];
      float r0 = bf2f((unsigned short)(u.x & 0xffffu));
      float r1 = bf2f((unsigned short)(u.x >> 16));
      float r2 = bf2f((unsigned short)(u.y & 0xffffu));
      float r3 = bf2f((unsigned short)(u.y >> 16));
      const float qa = qrs[ii][(2 * w) * RL + r];
      const float qb = qrs[ii][(2 * w + 1) * RL + r];
      s[ii][0][0] += qa * r0; s[ii][0][1] += qa * r1;
      s[ii][0][2] += qa * r2; s[ii][0][3] += qa * r3;
      s[ii][1][0] += qb * r0; s[ii][1][1] += qb * r1;
      s[ii][1][2] += qb * r2; s[ii][1][3] += qb * r3;
    }
  }

  // ---- phase B: within-wave softmax
  #pragma unroll
  for (int ii = 0; ii < 2; ++ii) {
    #pragma unroll
    for (int hh = 0; hh < 2; ++hh) {
      float v = fmaxf(fmaxf(s[ii][hh][0], s[ii][hh][1]),
                      fmaxf(s[ii][hh][2], s[ii][hh][3]));
      #pragma unroll
      for (int off = 32; off; off >>= 1) v = fmaxf(v, __shfl_xor(v, off));
      float4 p;
      p.x = __expf(s[ii][hh][0] - v); p.y = __expf(s[ii][hh][1] - v);
      p.z = __expf(s[ii][hh][2] - v); p.w = __expf(s[ii][hh][3] - v);
      float sum = p.x + p.y + p.z + p.w;
      #pragma unroll
      for (int off = 32; off; off >>= 1) sum += __shfl_xor(sum, off);
      const float rec = 1.f / sum;
      p.x *= rec; p.y *= rec; p.z *= rec; p.w *= rec;
      *(float4*)&at[(ii * NH + 2 * w + hh) * ATP + 4 * l] = p;
    }
  }

  // ---- phase C: ar[ii][h][r] = sum_j at[h][j] * relT[r][j]
  #pragma unroll
  for (int ii = 0; ii < 2; ++ii) {
    const int r = l & 15, sl = l >> 4;
    const int h = 2 * w + (sl & 1);
    const int jb = (sl >> 1) * 128;
    const float* atp = at + (ii * NH + h) * ATP + jb;
    const unsigned int* rr_ = &rldsT[(ii * RL + r) * RLT + (jb >> 1)];
    float a = 0.f;
    #pragma unroll 8
    for (int u = 0; u < 64; ++u) {
      unsigned int x = rr_[u];
      a += atp[2 * u]     * bf2f((unsigned short)(x & 0xffffu));
      a += atp[2 * u + 1] * bf2f((unsigned short)(x >> 16));
    }
    a += __shfl_xor(a, 32);
    if (l < 32) ar[ii][32 * w + l] = a;
  }
  __syncthreads();   // at cross-wave; rldsT dead -> part alias

  // ---- phase D: partial wv over j in [64w,64w+64); c = 4l..4l+3
  {
    const int h = l >> 3;
    const ushort4* vp = (const ushort4*)(VnB + (size_t)b * NN * FD) + l;
    const float* ap0 = at + h * ATP + 64 * w;
    const float* ap1 = at + (NH + h) * ATP + 64 * w;
    float4 a0 = make_float4(0,0,0,0), a1 = make_float4(0,0,0,0);
    #pragma unroll 4
    for (int jj = 0; jj < 64; ++jj) {
      ushort4 u = vp[(64 * w + jj) * (FD / 4)];
      float4 v = make_float4(bf2f(u.x), bf2f(u.y), bf2f(u.z), bf2f(u.w));
      float p0 = ap0[jj], p1 = ap1[jj];
      a0.x += p0*v.x; a0.y += p0*v.y; a0.z += p0*v.z; a0.w += p0*v.w;
      a1.x += p1*v.x; a1.y += p1*v.y; a1.z += p1*v.z; a1.w += p1*v.w;
    }
    ((float4*)part)[w * 64 + l]       = a0;
    ((float4*)part)[(4 + w) * 64 + l] = a1;
  }
  __syncthreads();

  // ---- phase E: reduce partials + Wv_r term -> wvB (bf16)
  {
    const int c = tid, h2 = c >> 5;
    float s0 = part[c] + part[FD + c] + part[2*FD + c] + part[3*FD + c];
    float s1 = part[4*FD + c] + part[5*FD + c] + part[6*FD + c] + part[7*FD + c];
    #pragma unroll
    for (int r = 0; r < RL; ++r) {
      const float wvr = Wv[(FD + r) * FD + c];
      s0 += ar[0][h2 * RL + r] * wvr;
      s1 += ar[1][h2 * RL + r] * wvr;
    }
    unsigned short* wvB = (unsigned short*)(ws + OFF_WVB);
    wvB[(b * NN + i0) * FD + c]     = f2bf(s0);
    wvB[(b * NN + i0 + 1) * FD + c] = f2bf(s1);
  }
}

// ---------------- Kernel 3: MFMA out-GEMM + residual
__global__ __launch_bounds__(256) void k_out10(
    const float* __restrict__ nf, const float* __restrict__ bo,
    float* __restrict__ out, float* __restrict__ ws) {
  const unsigned short* wvB = (const unsigned short*)(ws + OFF_WVB);
  const unsigned short* WoT = (const unsigned short*)(ws + OFF_WT) + 3 * FD * FD;
  const int c0 = blockIdx.y * 64;
  const int m0 = blockIdx.x * 64 + (threadIdx.x >> 6) * 16;
  const int l = threadIdx.x & 63;
  const int ar = l & 15, kg = l >> 4;
  f32x4 acc[4];
  #pragma unroll
  for (int nt = 0; nt < 4; ++nt) acc[nt] = (f32x4){0.f, 0.f, 0.f, 0.f};
  #pragma unroll
  for (int ks = 0; ks < 8; ++ks) {
    bf16x8 a = *(const bf16x8*)(wvB + (m0 + ar) * FD + ks * 32 + kg * 8);
    #pragma unroll
    for (int nt = 0; nt < 4; ++nt) {
      bf16x8 b = *(const bf16x8*)(WoT + (c0 + nt * 16 + ar) * FD + ks * 32 + kg * 8);
      acc[nt] = __builtin_amdgcn_mfma_f32_16x16x32_bf16(a, b, acc[nt], 0, 0, 0);
    }
  }
  #pragma unroll
  for (int nt = 0; nt < 4; ++nt) {
    const int cc = c0 + nt * 16 + ar;
    const float bb = bo[cc];
    #pragma unroll
    for (int i = 0; i < 4; ++i) {
      const int m = m0 + kg * 4 + i;
      out[m * FD + cc] = nf[m * FD + cc] + acc[nt][i] + bb;
    }
  }
}

extern "C" void kernel_launch(void* const* d_in, const int* in_sizes, int n_in,
                              void* d_out, int out_size, void* d_ws, size_t ws_size,
                              hipStream_t stream) {
  const float* nf  = (const float*)d_in[0];
  const float* rel = (const float*)d_in[1];
  const float* Wq  = (const float*)d_in[2];
  const float* bq  = (const float*)d_in[3];
  const float* Wk  = (const float*)d_in[4];
  const float* bk  = (const float*)d_in[5];
  const float* Wv  = (const float*)d_in[6];
  const float* bv  = (const float*)d_in[7];
  const float* Wo  = (const float*)d_in[8];
  const float* bo  = (const float*)d_in[9];
  float* out = (float*)d_out;
  float* ws  = (float*)d_ws;

  k_prep  <<<dim3(16, 5), 256, 0, stream>>>(nf, Wq, Wk, Wv, Wo, ws);
  k_proj  <<<dim3(16, 12), 256, 0, stream>>>(bq, bk, bv, ws);
  k_attn10<<<512, 256, 0, stream>>>(rel, Wk, Wv, ws);
  k_out10 <<<dim3(16, 4), 256, 0, stream>>>(nf, bo, out, ws);
}

// Round 11
// 38.272 us; speedup vs baseline: 1.1419x; 1.1419x over previous
//
#include <hip/hip_runtime.h>

// GeometricAttention: B=4, N=256, FDIM=256, REL=16, H=8, D=32
//   K[b,i,j] = Kn[b,j] + rel[b,i,j] @ Wk_r          (Kn = nf@Wk_f + bk)
//   scores   = Q.Kn^T + Qr.rel^T                     (Qr = per-head Q @ Wk_r^T)
//   sum_j attn*V = attn@Vn + (attn@rel)@Wv_r         (Vn = nf@Wv_f + bv)
// Round 11: attention core on MFMA. QI=4 rows/block, 256 blocks x 512 thr,
// wave=head. QK/arel/PV/out-GEMM all mfma_f32_16x16x32_bf16 with the
// fragment mappings hardware-verified by r10's k_proj (A row=lane&15,
// k=(lane>>4)*8+e; B col=lane&15 same k; D col=lane&15 row=(lane>>4)*4+reg).

#define BB 4
#define NN 256
#define FD 256
#define RL 16
#define NH 8
#define HD 32
#define QI 4

typedef __attribute__((ext_vector_type(8))) short bf16x8;
typedef __attribute__((ext_vector_type(4))) float f32x4;

// ws layout (float offsets); each bf16 matrix of 4*256*256 = 131072 floats
#define OFF_QB   0                          // ushort Qb[b][i][f]  (scaled)
#define OFF_KNA  131072                     // ushort Kn[b][j][f]
#define OFF_VNT  262144                     // ushort VnT[b][f][j]
#define OFF_NFB  393216                     // ushort nfB[1024][256]
#define OFF_WT   524288                     // ushort WT[4][c][k]: Wq,Wk_f,Wv_f,Wo

static __device__ __forceinline__ unsigned short f2bf(float x) {
  unsigned int u = __float_as_uint(x);
  unsigned int r = (u + 0x7fffu + ((u >> 16) & 1u)) >> 16;   // RNE
  return (unsigned short)r;
}
static __device__ __forceinline__ float bf2f(unsigned short h) {
  return __uint_as_float(((unsigned int)h) << 16);
}

// ---------------- Kernel 0: prep — nf->bf16; W transposes to WT[c][k] bf16
__global__ __launch_bounds__(256) void k_prep(
    const float* __restrict__ nf,
    const float* __restrict__ Wq, const float* __restrict__ Wk,
    const float* __restrict__ Wv, const float* __restrict__ Wo,
    float* __restrict__ ws) {
  const int tid = threadIdx.x;
  const int sel = blockIdx.y;          // 0..3: Wq/Wk_f/Wv_f/Wo -> WT; 4: nfB
  if (sel == 4) {
    unsigned short* nfB = (unsigned short*)(ws + OFF_NFB);
    const int base = blockIdx.x * 16384;
    #pragma unroll 8
    for (int k = 0; k < 64; ++k) {
      const int idx = base + k * 256 + tid;
      nfB[idx] = f2bf(nf[idx]);
    }
    return;
  }
  const float* W = (sel == 0) ? Wq : (sel == 1) ? Wk : (sel == 2) ? Wv : Wo;
  unsigned short* WT = (unsigned short*)(ws + OFF_WT) + sel * FD * FD;
  __shared__ unsigned short t[64][72];
  const int tx = blockIdx.x & 3, ty = blockIdx.x >> 2;   // 64x64 tile
  const int cx = tid & 63, r0 = tid >> 6;
  #pragma unroll
  for (int rr = r0; rr < 64; rr += 4)
    t[rr][cx] = f2bf(W[(ty * 64 + rr) * FD + tx * 64 + cx]);
  __syncthreads();
  #pragma unroll
  for (int rr = r0; rr < 64; rr += 4)
    WT[(tx * 64 + rr) * FD + ty * 64 + cx] = t[cx][rr];   // WT[c][k] = W[k][c]
}

// ---------------- Kernel 1: MFMA projections -> Qb / Kn / VnT (all bf16)
__global__ __launch_bounds__(256) void k_proj(
    const float* __restrict__ bq, const float* __restrict__ bk,
    const float* __restrict__ bv, float* __restrict__ ws) {
  const unsigned short* nfB = (const unsigned short*)(ws + OFF_NFB);
  const int mat = blockIdx.y >> 2;                 // 0=Qb, 1=Kn, 2=VnT
  const int c0 = (blockIdx.y & 3) * 64;
  const int m0 = blockIdx.x * 64 + (threadIdx.x >> 6) * 16;
  const int l = threadIdx.x & 63;
  const unsigned short* WT = (const unsigned short*)(ws + OFF_WT) + mat * FD * FD;
  const int ar = l & 15, kg = l >> 4;
  f32x4 acc[4];
  #pragma unroll
  for (int nt = 0; nt < 4; ++nt) acc[nt] = (f32x4){0.f, 0.f, 0.f, 0.f};
  #pragma unroll
  for (int ks = 0; ks < 8; ++ks) {
    bf16x8 a = *(const bf16x8*)(nfB + (m0 + ar) * FD + ks * 32 + kg * 8);
    #pragma unroll
    for (int nt = 0; nt < 4; ++nt) {
      bf16x8 b = *(const bf16x8*)(WT + (c0 + nt * 16 + ar) * FD + ks * 32 + kg * 8);
      acc[nt] = __builtin_amdgcn_mfma_f32_16x16x32_bf16(a, b, acc[nt], 0, 0, 0);
    }
  }
  if (mat == 0) {
    const float scale = 0.17677669529663687f;      // 1/sqrt(32)
    unsigned short* Qb = (unsigned short*)(ws + OFF_QB);
    #pragma unroll
    for (int nt = 0; nt < 4; ++nt) {
      const int cc = c0 + nt * 16 + ar;
      const float bb = bq[cc];
      #pragma unroll
      for (int i = 0; i < 4; ++i)
        Qb[(m0 + kg * 4 + i) * FD + cc] = f2bf((acc[nt][i] + bb) * scale);
    }
  } else if (mat == 1) {
    unsigned short* Kn = (unsigned short*)(ws + OFF_KNA);
    #pragma unroll
    for (int nt = 0; nt < 4; ++nt) {
      const int cc = c0 + nt * 16 + ar;
      const float bb = bk[cc];
      #pragma unroll
      for (int i = 0; i < 4; ++i)
        Kn[(m0 + kg * 4 + i) * FD + cc] = f2bf(acc[nt][i] + bb);
    }
  } else {
    unsigned short* VnT = (unsigned short*)(ws + OFF_VNT);
    const int b2 = m0 >> 8, j0 = (m0 & 255) + kg * 4;
    #pragma unroll
    for (int nt = 0; nt < 4; ++nt) {
      const int cc = c0 + nt * 16 + ar;
      const float bb = bv[cc];
      ushort4 v;
      v.x = f2bf(acc[nt][0] + bb); v.y = f2bf(acc[nt][1] + bb);
      v.z = f2bf(acc[nt][2] + bb); v.w = f2bf(acc[nt][3] + bb);
      *(ushort4*)&VnT[((size_t)b2 * FD + cc) * NN + j0] = v;
    }
  }
}

// ---------------- Kernel 2: full attention + output, MFMA core
__global__ __launch_bounds__(512, 2) void k_attn11(
    const float* __restrict__ rel,
    const float* __restrict__ Wk,
    const float* __restrict__ Wv,
    const float* __restrict__ nf,
    const float* __restrict__ bo,
    float* __restrict__ out,
    float* __restrict__ ws) {
  const unsigned short* QbG = (const unsigned short*)(ws + OFF_QB);
  const unsigned short* KnG = (const unsigned short*)(ws + OFF_KNA);
  const unsigned short* VTG = (const unsigned short*)(ws + OFF_VNT);
  const unsigned short* WoT = (const unsigned short*)(ws + OFF_WT) + 3 * FD * FD;

  // XCD-chunked swizzle over 256 blocks (bijective)
  const int bid = (blockIdx.x & 7) * 32 + (blockIdx.x >> 3);
  const int b  = bid >> 6;
  const int i0 = (bid & 63) * QI;
  const int tid = threadIdx.x;
  const int l = tid & 63, w = tid >> 6;
  const int l15 = l & 15, kg = l >> 4;

  __shared__ unsigned short Qb_l[QI * 264];          // [i][264]        2.1 KB
  __shared__ unsigned short relT[QI * 16 * 264];     // [(i*16+r)][j]  33.8 KB
  __shared__ unsigned short srelP2[8 * 1064];        // srel then P2   17.0 KB
  __shared__ float qr_l[QI * 8 * 16];                //                 2 KB
  __shared__ float ar_l[QI * 8 * 16];                //                 2 KB
  __shared__ unsigned short wv_l[QI * 264];          //                 2.1 KB

  // ---- stage Qb (2 bf16 per thread) + relT (transposed bf16)
  {
    const int t2 = tid * 2, row = t2 >> 8, col = t2 & 255;
    *(unsigned int*)&Qb_l[row * 264 + col] =
        *(const unsigned int*)(QbG + ((size_t)(b * NN + i0 + row)) * FD + col);
  }
  #pragma unroll
  for (int m = 0; m < 2; ++m) {
    const int p = tid + 512 * m, i = p >> 8, j = p & 255;
    const float4* rp = (const float4*)(rel + (((size_t)(b * NN + i0 + i)) * NN + j) * RL);
    #pragma unroll
    for (int q4 = 0; q4 < 4; ++q4) {
      float4 v = rp[q4];
      relT[(i * 16 + q4 * 4 + 0) * 264 + j] = f2bf(v.x);
      relT[(i * 16 + q4 * 4 + 1) * 264 + j] = f2bf(v.y);
      relT[(i * 16 + q4 * 4 + 2) * 264 + j] = f2bf(v.z);
      relT[(i * 16 + q4 * 4 + 3) * 264 + j] = f2bf(v.w);
    }
  }
  __syncthreads();

  // ---- qr[i][h][r] = Qb[i][h*32..] . Wk[256+r][h*32..]  (one output/thread)
  {
    const int i = tid >> 7, h = (tid >> 4) & 7, r = tid & 15;
    const unsigned int* qp = (const unsigned int*)&Qb_l[i * 264 + h * 32];
    const float* wrow = Wk + (FD + r) * FD + h * HD;
    float s = 0.f;
    #pragma unroll
    for (int d2 = 0; d2 < 16; ++d2) {
      unsigned int u = qp[d2];
      s += bf2f((unsigned short)(u & 0xffffu)) * wrow[2 * d2];
      s += bf2f((unsigned short)(u >> 16)) * wrow[2 * d2 + 1];
    }
    qr_l[(i * 8 + h) * 16 + r] = s;
  }
  __syncthreads();

  // ---- phase R: srel[i][h][j] = sum_r qr[i][h][r] * relT[i][r][j]
  {
    const int i = w & 3, jh = w >> 2;
    const int j0 = jh * 128 + l;                  // j0 and j0+64
    float rv0[16], rv1[16];
    #pragma unroll
    for (int r = 0; r < 16; ++r) {
      rv0[r] = bf2f(relT[(i * 16 + r) * 264 + j0]);
      rv1[r] = bf2f(relT[(i * 16 + r) * 264 + j0 + 64]);
    }
    #pragma unroll
    for (int h = 0; h < 8; ++h) {
      const float* qv = &qr_l[(i * 8 + h) * 16];
      float s0 = 0.f, s1 = 0.f;
      #pragma unroll
      for (int r = 0; r < 16; ++r) { s0 += qv[r] * rv0[r]; s1 += qv[r] * rv1[r]; }
      srelP2[(i * 8 + h) * 264 + j0]      = f2bf(s0);
      srelP2[(i * 8 + h) * 264 + j0 + 64] = f2bf(s1);
    }
  }
  __syncthreads();

  // ---- QK^T MFMA (wave = head) + srel add + softmax (in registers)
  const int h = w;
  f32x4 acc[16];
  {
    bf16x8 afrag = *(const bf16x8*)&Qb_l[(l15 & 3) * 264 + h * 32 + kg * 8];
    #pragma unroll
    for (int nt = 0; nt < 16; ++nt) {
      bf16x8 bfrag = *(const bf16x8*)(KnG + ((size_t)(b * NN + nt * 16 + l15)) * FD
                                      + h * 32 + kg * 8);
      acc[nt] = __builtin_amdgcn_mfma_f32_16x16x32_bf16(
          afrag, bfrag, (f32x4){0.f, 0.f, 0.f, 0.f}, 0, 0, 0);
    }
    #pragma unroll
    for (int nt = 0; nt < 16; ++nt) {
      #pragma unroll
      for (int ireg = 0; ireg < 4; ++ireg) {
        const int iC = (kg * 4 + ireg) & 3;       // valid rows: kg==0
        acc[nt][ireg] += bf2f(srelP2[(iC * 8 + h) * 264 + nt * 16 + l15]);
      }
    }
  }
  #pragma unroll
  for (int ireg = 0; ireg < 4; ++ireg) {
    float mx = acc[0][ireg];
    #pragma unroll
    for (int nt = 1; nt < 16; ++nt) mx = fmaxf(mx, acc[nt][ireg]);
    mx = fmaxf(mx, __shfl_xor(mx, 1)); mx = fmaxf(mx, __shfl_xor(mx, 2));
    mx = fmaxf(mx, __shfl_xor(mx, 4)); mx = fmaxf(mx, __shfl_xor(mx, 8));
    float sum = 0.f;
    #pragma unroll
    for (int nt = 0; nt < 16; ++nt) {
      float e = __expf(acc[nt][ireg] - mx);
      acc[nt][ireg] = e; sum += e;
    }
    sum += __shfl_xor(sum, 1); sum += __shfl_xor(sum, 2);
    sum += __shfl_xor(sum, 4); sum += __shfl_xor(sum, 8);
    const float rec = 1.f / sum;
    #pragma unroll
    for (int nt = 0; nt < 16; ++nt) acc[nt][ireg] *= rec;
  }
  __syncthreads();   // all srel reads done; srelP2 becomes P2

  // ---- P2[h][i][j] stores (valid rows = kg 0 -> lanes 0..15)
  if (l < 16) {
    #pragma unroll
    for (int nt = 0; nt < 16; ++nt)
      #pragma unroll
      for (int ireg = 0; ireg < 4; ++ireg)
        srelP2[h * 1064 + ireg * 264 + nt * 16 + l] = f2bf(acc[nt][ireg]);
  }
  __syncthreads();

  // ---- arel MFMA: ar[i](r,h) = relT[i](r,j) @ P2T (waves 0..3, i = w)
  if (w < 4) {
    const int i = w;
    const int colh = l15 & 7;
    f32x4 aa = (f32x4){0.f, 0.f, 0.f, 0.f};
    #pragma unroll
    for (int ks = 0; ks < 8; ++ks) {
      bf16x8 a = *(const bf16x8*)&relT[(i * 16 + l15) * 264 + ks * 32 + kg * 8];
      bf16x8 bb = *(const bf16x8*)&srelP2[colh * 1064 + i * 264 + ks * 32 + kg * 8];
      aa = __builtin_amdgcn_mfma_f32_16x16x32_bf16(a, bb, aa, 0, 0, 0);
    }
    if (l15 < 8) {
      #pragma unroll
      for (int ireg = 0; ireg < 4; ++ireg)
        ar_l[(i * 8 + l15) * 16 + kg * 4 + ireg] = aa[ireg];
    }
  }
  __syncthreads();

  // ---- wv_rel: wv[i][c] = sum_r ar[i][h(c)][r] * Wv[256+r][c]
  {
    const int c = tid & 255, ii0 = tid >> 8, hc = c >> 5;
    float wvv[16];
    #pragma unroll
    for (int r = 0; r < 16; ++r) wvv[r] = Wv[(FD + r) * FD + c];
    #pragma unroll
    for (int k2 = 0; k2 < 2; ++k2) {
      const int i = ii0 + 2 * k2;
      const float* ap = &ar_l[(i * 8 + hc) * 16];
      float s = 0.f;
      #pragma unroll
      for (int r = 0; r < 16; ++r) s += ap[r] * wvv[r];
      wv_l[i * 264 + c] = f2bf(s);
    }
  }
  __syncthreads();

  // ---- PV MFMA (swapped): O^T(d,i) = VnT(d,j) @ P2(j,i), wave = head
  {
    const int coli = l15 & 3;
    f32x4 o0 = (f32x4){0.f, 0.f, 0.f, 0.f};
    f32x4 o1 = (f32x4){0.f, 0.f, 0.f, 0.f};
    #pragma unroll
    for (int ks = 0; ks < 8; ++ks) {
      bf16x8 bb = *(const bf16x8*)&srelP2[h * 1064 + coli * 264 + ks * 32 + kg * 8];
      bf16x8 a0 = *(const bf16x8*)(VTG + ((size_t)(b * FD + h * 32 + l15)) * NN
                                   + ks * 32 + kg * 8);
      bf16x8 a1 = *(const bf16x8*)(VTG + ((size_t)(b * FD + h * 32 + 16 + l15)) * NN
                                   + ks * 32 + kg * 8);
      o0 = __builtin_amdgcn_mfma_f32_16x16x32_bf16(a0, bb, o0, 0, 0, 0);
      o1 = __builtin_amdgcn_mfma_f32_16x16x32_bf16(a1, bb, o1, 0, 0, 0);
    }
    if (l15 < 4) {
      #pragma unroll
      for (int ireg = 0; ireg < 4; ++ireg) {
        const int c0_ = h * 32 + kg * 4 + ireg;
        const int c1_ = c0_ + 16;
        const int idx0 = l15 * 264 + c0_;
        const int idx1 = l15 * 264 + c1_;
        wv_l[idx0] = f2bf(bf2f(wv_l[idx0]) + o0[ireg]);
        wv_l[idx1] = f2bf(bf2f(wv_l[idx1]) + o1[ireg]);
      }
    }
  }
  __syncthreads();

  // ---- out-GEMM MFMA: out[i][cc] = nf + wv @ Wo + bo (wave w: cc in [32w,32w+32))
  {
    const int c0_ = w * 32;
    f32x4 oa0 = (f32x4){0.f, 0.f, 0.f, 0.f};
    f32x4 oa1 = (f32x4){0.f, 0.f, 0.f, 0.f};
    #pragma unroll
    for (int ks = 0; ks < 8; ++ks) {
      bf16x8 a = *(const bf16x8*)&wv_l[(l15 & 3) * 264 + ks * 32 + kg * 8];
      bf16x8 b0 = *(const bf16x8*)(WoT + (c0_ + l15) * FD + ks * 32 + kg * 8);
      bf16x8 b1 = *(const bf16x8*)(WoT + (c0_ + 16 + l15) * FD + ks * 32 + kg * 8);
      oa0 = __builtin_amdgcn_mfma_f32_16x16x32_bf16(a, b0, oa0, 0, 0, 0);
      oa1 = __builtin_amdgcn_mfma_f32_16x16x32_bf16(a, b1, oa1, 0, 0, 0);
    }
    if (l < 16) {
      #pragma unroll
      for (int ireg = 0; ireg < 4; ++ireg) {
        const int row = (b * NN + i0 + ireg) * FD;
        const int cc0 = c0_ + l, cc1 = c0_ + 16 + l;
        out[row + cc0] = nf[row + cc0] + oa0[ireg] + bo[cc0];
        out[row + cc1] = nf[row + cc1] + oa1[ireg] + bo[cc1];
      }
    }
  }
}

extern "C" void kernel_launch(void* const* d_in, const int* in_sizes, int n_in,
                              void* d_out, int out_size, void* d_ws, size_t ws_size,
                              hipStream_t stream) {
  const float* nf  = (const float*)d_in[0];
  const float* rel = (const float*)d_in[1];
  const float* Wq  = (const float*)d_in[2];
  const float* bq  = (const float*)d_in[3];
  const float* Wk  = (const float*)d_in[4];
  const float* bk  = (const float*)d_in[5];
  const float* Wv  = (const float*)d_in[6];
  const float* bv  = (const float*)d_in[7];
  const float* Wo  = (const float*)d_in[8];
  const float* bo  = (const float*)d_in[9];
  float* out = (float*)d_out;
  float* ws  = (float*)d_ws;

  k_prep  <<<dim3(16, 5), 256, 0, stream>>>(nf, Wq, Wk, Wv, Wo, ws);
  k_proj  <<<dim3(16, 12), 256, 0, stream>>>(bq, bk, bv, ws);
  k_attn11<<<BB * NN / QI, 512, 0, stream>>>(rel, Wk, Wv, nf, bo, out, ws);
}